// Round 15
// baseline (142.276 us; speedup 1.0000x reference)
//
#include <hip/hip_runtime.h>
#include <hip/hip_fp16.h>

static constexpr int Hh = 384;
static constexpr int Ww = 1280;
static constexpr int HW = Hh * Ww;            // 491520
static constexpr int NPIX = 2 * HW;
static constexpr int TILE_I = 48;             // output tile rows
static constexpr int TILE_J = 40;             // output tile cols
static constexpr int S_STEPS = 8;             // steps per launch; 24 = 3 x 8
static constexpr int RI = TILE_I + 2 * S_STEPS;   // 64
static constexpr int RJ = TILE_J + 2 * S_STEPS;   // 56 (== 0 mod 4: quad-aligned rows)
static constexpr int RR = RI * RJ;            // 3584
static constexpr int PAD = 8;                 // LDS guard band (front + per-buffer tail)
static constexpr int RRP = RR + PAD;          // padded buffer stride
static constexpr int NQROW = RJ / 4;          // 14 quads per row (exact)
static constexpr int QROWS = RI - 2;          // 62 computable rows (1..62)
static constexpr int NQUAD = QROWS * NQROW;   // 868 quads
static constexpr int BLOCK = 512;
static constexpr int PPQ = RR / BLOCK;        // 7 region px / thread (exact)
static constexpr int PPQd = (NQUAD + BLOCK - 1) / BLOCK;  // 2 quads / thread
static constexpr int TI_T = Hh / TILE_I;      // 8
static constexpr int TJ_T = Ww / TILE_J;      // 32
static constexpr int GRID = 2 * TI_T * TJ_T;  // 512 = exactly 2 blocks/CU
static constexpr int NXCD = 8;
static constexpr int CHUNK = GRID / NXCD;     // 64 (512 % 8 == 0 -> bijective)
static constexpr float EPSF = 1e-9f;

// k order matches reference PADS: (di,dj) =
// k:   0       1       2       3       4       5       6       7
//    (+1,+1) (+1,0) (+1,-1) (0,+1) (0,-1) (-1,+1) (-1,0) (-1,-1)
__device__ __constant__ int DI_c[8] = { 1, 1, 1, 0, 0, -1, -1, -1 };
__device__ __constant__ int DJ_c[8] = { 1, 0, -1, 1, -1, 1, 0, -1 };

static __device__ __forceinline__ int iclamp(int v, int lo, int hi) {
    return min(max(v, lo), hi);
}

// Precompute per pixel: w'_k (fp16, zeroed where sparse-clamped) and
// C = m ? raw : (1-gate_sum)*raw. (r14-proven; one launch, ~10us.)
__global__ void affinity_norm(const float* __restrict__ g,
                              const float* __restrict__ raw,
                              const float* __restrict__ sparse,
                              __half* __restrict__ wbuf,
                              float* __restrict__ cbuf) {
    int idx = blockIdx.x * blockDim.x + threadIdx.x;
    if (idx >= NPIX) return;
    int b = idx / HW;
    int r = idx - b * HW;
    int i = r / Ww;
    int j = r - i * Ww;

    const float* gb = g + (size_t)b * 8 * HW;
    float v[8];
    float a = EPSF;
#pragma unroll
    for (int k = 0; k < 8; k++) {
        int ii = i + DI_c[k], jj = j + DJ_c[k];
        float gv = 0.0f;
        if (ii >= 0 && ii < Hh && jj >= 0 && jj < Ww)
            gv = gb[k * HW + ii * Ww + jj];
        v[k] = gv;
        a += fabsf(gv);
    }
    float inv = 1.0f / a, gs = 0.0f;
#pragma unroll
    for (int k = 0; k < 8; k++) { v[k] *= inv; gs += v[k]; }

    float rawv = raw[idx];
    bool m = sparse[idx] > 0.0f;   // sparse >= 0 always; sign(s)==1 iff s>0
    cbuf[idx] = m ? rawv : (1.0f - gs) * rawv;
    __half wv[8];
#pragma unroll
    for (int k = 0; k < 8; k++) wv[k] = __float2half(m ? 0.0f : v[k]);
    *(float4*)(wbuf + (size_t)idx * 8) = *(const float4*)wv;
}

// Round-15: r14's engine (3x8, tile 48x40, precomputed w/C — 129.0us best)
// with the inner loop upgraded pairs -> QUADS (4 px, 16B-aligned):
//   per quad-row the 6-tap span = 1 ds_read_b128 + 2 edge b32 (merge to
//   ds_read2), write = 1 ds_write_b128. LDS ops per 4px: 10 vs pairs' 16;
//   FMAs are float4 component ops (4 independent chains). r14's steps ran
//   ~5-7x above LDS/VALU throughput floor (latency-bound phases); fewer,
//   wider LDS ops + deeper ILP attacks exactly that.
//  - Quads span the FULL region width (cols 0..55). Edge px (ring 0) get
//    written with pad-influenced values; ring-r values are only read
//    through step r+1 by construction, so ring-0 outputs are never read
//    and never stored (write gate mring>=8 selects exactly the full-center
//    quads: cols 8..47, rows 8..55). Same induction as the r8-proven
//    pair-partner argument.
//  - LDS guard band: +-8 floats around each buffer, zeroed once; edge-quad
//    taps (col -1 of row 1 / col 56 of row 62) land there, bounded.
//  - Persistent regs: wq 64 + Cq 8 + pq 2 = 74 (r14 proven no-spill at 76)
//    under the (512,2) 128-VGPR budget (knob ledger r3-r6).
template <bool FIRST>
__global__ __launch_bounds__(BLOCK, 2)
void mega(
    const __half* __restrict__ wbuf,
    const float* __restrict__ cbuf,
    const float* blur,
    const float* din,
    float* __restrict__ dout)
{
    __shared__ float sdraw[PAD + 2 * RRP];

    const int tid = threadIdx.x;
    // XCD-aware bijective swizzle (512 = 8*64).
    int bx = ((int)blockIdx.x % NXCD) * CHUNK + (int)blockIdx.x / NXCD;
    const int tj = bx % TJ_T; bx /= TJ_T;
    const int ti = bx % TI_T;
    const int b  = bx / TI_T;
    const int oi = ti * TILE_I - S_STEPS;  // region origin (image coords)
    const int oj = tj * TILE_J - S_STEPS;

    const float* dinb = (FIRST ? blur : din) + (size_t)b * HW;
    float* const sbase = sdraw + PAD;

    // --- zero the guard bands (front pad, tail of buf0, tail of buf1) ---
    if (tid < PAD) {
        sdraw[tid] = 0.0f;
        sbase[RR + tid] = 0.0f;          // buf0 tail (= buf1's front guard)
        sbase[RRP + RR + tid] = 0.0f;    // buf1 tail
    }

    // --- stage d0 over the whole region (image-clamped; 7x512 exact) ---
#pragma unroll
    for (int q = 0; q < PPQ; q++) {
        int p = tid + q * BLOCK;
        int ri = p / RJ, rj = p - ri * RJ;
        int gi = iclamp(oi + ri, 0, Hh - 1);
        int gj = iclamp(oj + rj, 0, Ww - 1);
        sbase[p] = dinb[gi * Ww + gj];
    }

    // --- load precomputed weights + C per QUAD.
    // wq[q][k] = (w_k[px0..px3]); Cq[q] = (C0..C3);
    // pq[q] = region offset of px0 (low 16) | maxring << 16 ---
    float4 wq[PPQd][8];
    float4 Cq[PPQd];
    int    pq[PPQd];
#pragma unroll
    for (int q = 0; q < PPQd; q++) {
        int qi = tid + q * BLOCK;
        if (qi < NQUAD) {
            int r0 = qi / NQROW;
            int c  = qi - r0 * NQROW;
            int ri = 1 + r0;
            int rj = 4 * c;
            int p  = ri * RJ + rj;
            int rr_ = min(ri, RI - 1 - ri);
            float wt[8][4], Ct[4];
            int mring = 0;
#pragma unroll
            for (int x = 0; x < 4; x++) {
                mring = max(mring, min(rr_, min(rj + x, RJ - 1 - (rj + x))));
                int gi = iclamp(oi + ri, 0, Hh - 1);
                int gj = iclamp(oj + rj + x, 0, Ww - 1);
                int idx = b * HW + gi * Ww + gj;
                float4 w4 = *(const float4*)(wbuf + (size_t)idx * 8);
                const __half2* wh = (const __half2*)&w4;
                float2 w01 = __half22float2(wh[0]);
                float2 w23 = __half22float2(wh[1]);
                float2 w45 = __half22float2(wh[2]);
                float2 w67 = __half22float2(wh[3]);
                wt[0][x] = w01.x; wt[1][x] = w01.y;
                wt[2][x] = w23.x; wt[3][x] = w23.y;
                wt[4][x] = w45.x; wt[5][x] = w45.y;
                wt[6][x] = w67.x; wt[7][x] = w67.y;
                Ct[x] = cbuf[idx];
            }
            pq[q] = p | (mring << 16);
#pragma unroll
            for (int k = 0; k < 8; k++)
                wq[q][k] = make_float4(wt[k][0], wt[k][1], wt[k][2], wt[k][3]);
            Cq[q] = make_float4(Ct[0], Ct[1], Ct[2], Ct[3]);
        } else {
            pq[q] = 0;                     // mring 0 -> never active
            Cq[q] = make_float4(0.f, 0.f, 0.f, 0.f);
#pragma unroll
            for (int k = 0; k < 8; k++)
                wq[q][k] = make_float4(0.f, 0.f, 0.f, 0.f);
        }
    }
    __syncthreads();

#define QUAD_TAPS(s0, p)                                               \
    float4 um = *(const float4*)((s0) + (p) - RJ);                     \
    float  ul = (s0)[(p) - RJ - 1], ur = (s0)[(p) - RJ + 4];           \
    float4 mm = *(const float4*)((s0) + (p));                          \
    float  ml = (s0)[(p) - 1],      mr = (s0)[(p) + 4];                \
    float4 dm = *(const float4*)((s0) + (p) + RJ);                     \
    float  dl = (s0)[(p) + RJ - 1], dr = (s0)[(p) + RJ + 4];

#define FMA4(W, a0, a1, a2, a3)                                        \
    acc.x = fmaf((W).x, (a0), acc.x); acc.y = fmaf((W).y, (a1), acc.y);\
    acc.z = fmaf((W).z, (a2), acc.z); acc.w = fmaf((W).w, (a3), acc.w);

#define QUAD_BODY(q)                                                   \
    float4 acc = Cq[q];                                                \
    FMA4(wq[q][0], dm.y, dm.z, dm.w, dr);   /* (+1,+1) */              \
    FMA4(wq[q][1], dm.x, dm.y, dm.z, dm.w); /* (+1, 0) */              \
    FMA4(wq[q][2], dl,   dm.x, dm.y, dm.z); /* (+1,-1) */              \
    FMA4(wq[q][3], mm.y, mm.z, mm.w, mr);   /* ( 0,+1) */              \
    FMA4(wq[q][4], ml,   mm.x, mm.y, mm.z); /* ( 0,-1) */              \
    FMA4(wq[q][5], um.y, um.z, um.w, ur);   /* (-1,+1) */              \
    FMA4(wq[q][6], um.x, um.y, um.z, um.w); /* (-1, 0) */              \
    FMA4(wq[q][7], ul,   um.x, um.y, um.z); /* (-1,-1) */

    // --- steps 1..7 in LDS; step s touches only quads with mring >= s ---
    int cur = 0;
#pragma unroll 1
    for (int s = 1; s < S_STEPS; ++s) {
        const float* s0 = sbase + cur * RRP;
        float* s1 = sbase + (cur ^ 1) * RRP;
#pragma unroll
        for (int q = 0; q < PPQd; q++) {
            if ((pq[q] >> 16) >= s) {
                int p = pq[q] & 0xffff;
                QUAD_TAPS(s0, p);
                QUAD_BODY(q);
                *(float4*)(s1 + p) = acc;
            }
        }
        __syncthreads();
        cur ^= 1;
    }

    // --- step 8: mring >= 8 selects exactly the full-center quads
    // (rows 8..55, cols 8..47); single float4 global store (16B aligned:
    // oj, rj both == 0 mod 4). ---
    const float* s0 = sbase + cur * RRP;
#pragma unroll
    for (int q = 0; q < PPQd; q++) {
        if ((pq[q] >> 16) >= S_STEPS) {
            int p = pq[q] & 0xffff;
            QUAD_TAPS(s0, p);
            QUAD_BODY(q);
            int ri = p / RJ, rj = p - ri * RJ;
            *(float4*)(dout + b * HW + (oi + ri) * Ww + (oj + rj)) = acc;
        }
    }
#undef QUAD_TAPS
#undef FMA4
#undef QUAD_BODY
}

extern "C" void kernel_launch(void* const* d_in, const int* in_sizes, int n_in,
                              void* d_out, int out_size, void* d_ws, size_t ws_size,
                              hipStream_t stream) {
    const float* guidance = (const float*)d_in[0];
    const float* blur     = (const float*)d_in[1];
    const float* sparse   = (const float*)d_in[2];
    float* out = (float*)d_out;

    char* ws = (char*)d_ws;
    float* bufA = (float*)ws;
    float* bufB = bufA + NPIX;
    __half* wbuf = (__half*)(bufB + NPIX);          // NPIX*8 fp16 = 15.7 MB
    float*  cbuf = (float*)(wbuf + (size_t)NPIX * 8);

    const int threads = 256;
    const int blocks = (NPIX + threads - 1) / threads;
    affinity_norm<<<blocks, threads, 0, stream>>>(guidance, blur, sparse, wbuf, cbuf);

    // 24 steps = 3 launches x 8 fused steps
    mega<true ><<<GRID, BLOCK, 0, stream>>>(wbuf, cbuf, blur, nullptr, bufA);
    mega<false><<<GRID, BLOCK, 0, stream>>>(wbuf, cbuf, nullptr, bufA, bufB);
    mega<false><<<GRID, BLOCK, 0, stream>>>(wbuf, cbuf, nullptr, bufB, out);
}

// Round 16
// 134.150 us; speedup vs baseline: 1.0606x; 1.0606x over previous
//
#include <hip/hip_runtime.h>
#include <hip/hip_fp16.h>

static constexpr int Hh = 384;
static constexpr int Ww = 1280;
static constexpr int HW = Hh * Ww;            // 491520
static constexpr int NPIX = 2 * HW;
static constexpr int TILE_I = 32;             // output tile rows
static constexpr int TILE_J = 40;             // output tile cols
static constexpr int S_STEPS = 8;             // steps per launch; 24 = 3 x 8
static constexpr int RI = TILE_I + 2 * S_STEPS;   // 48
static constexpr int RJ = TILE_J + 2 * S_STEPS;   // 56
static constexpr int RR = RI * RJ;            // 2688
static constexpr int II = RI - 2;             // 46 interior rows
static constexpr int IJ = RJ - 2;             // 54 interior cols
static constexpr int NPAIR_ROW = IJ / 2;      // 27 pairs/row (exact)
static constexpr int NPAIR = II * NPAIR_ROW;  // 1242 pairs
static constexpr int BLOCK = 512;
static constexpr int PPQ = (RR + BLOCK - 1) / BLOCK;      // 6 region px / thread
static constexpr int PPR = (NPAIR + BLOCK - 1) / BLOCK;   // 3 pairs / thread
static constexpr int TI_T = Hh / TILE_I;      // 12
static constexpr int TJ_T = Ww / TILE_J;      // 32
static constexpr int GRID = 2 * TI_T * TJ_T;  // 768 = exactly 3 blocks/CU
static constexpr int NXCD = 8;
static constexpr int CHUNK = GRID / NXCD;     // 96 (768 % 8 == 0 -> bijective)
static constexpr float EPSF = 1e-9f;

// k order matches reference PADS: (di,dj) =
// k:   0       1       2       3       4       5       6       7
//    (+1,+1) (+1,0) (+1,-1) (0,+1) (0,-1) (-1,+1) (-1,0) (-1,-1)
__device__ __constant__ int DI_c[8] = { 1, 1, 1, 0, 0, -1, -1, -1 };
__device__ __constant__ int DJ_c[8] = { 1, 0, -1, 1, -1, 1, 0, -1 };

static __device__ __forceinline__ int iclamp(int v, int lo, int hi) {
    return min(max(v, lo), hi);
}

// Precompute per pixel: w'_k (fp16, zeroed where sparse-clamped) and
// C = m ? raw : (1-gate_sum)*raw. (r14-proven; one launch, ~10us.)
__global__ void affinity_norm(const float* __restrict__ g,
                              const float* __restrict__ raw,
                              const float* __restrict__ sparse,
                              __half* __restrict__ wbuf,
                              float* __restrict__ cbuf) {
    int idx = blockIdx.x * blockDim.x + threadIdx.x;
    if (idx >= NPIX) return;
    int b = idx / HW;
    int r = idx - b * HW;
    int i = r / Ww;
    int j = r - i * Ww;

    const float* gb = g + (size_t)b * 8 * HW;
    float v[8];
    float a = EPSF;
#pragma unroll
    for (int k = 0; k < 8; k++) {
        int ii = i + DI_c[k], jj = j + DJ_c[k];
        float gv = 0.0f;
        if (ii >= 0 && ii < Hh && jj >= 0 && jj < Ww)
            gv = gb[k * HW + ii * Ww + jj];
        v[k] = gv;
        a += fabsf(gv);
    }
    float inv = 1.0f / a, gs = 0.0f;
#pragma unroll
    for (int k = 0; k < 8; k++) { v[k] *= inv; gs += v[k]; }

    float rawv = raw[idx];
    bool m = sparse[idx] > 0.0f;   // sparse >= 0 always; sign(s)==1 iff s>0
    cbuf[idx] = m ? rawv : (1.0f - gs) * rawv;
    __half wv[8];
#pragma unroll
    for (int k = 0; k < 8; k++) wv[k] = __float2half(m ? 0.0f : v[k]);
    *(float4*)(wbuf + (size_t)idx * 8) = *(const float4*)wv;
}

// Round-16: r14's engine (3x8, precomputed w/C, pair inner loop -- the
// 129.0us best; r15 quads regressed) re-tiled for 3 blocks/CU:
//   tile 32x40, region 48x56, LDS 21.5KB x 3 = 64.5KB, grid 768 = 3/CU
//   exact -> 24 waves/CU (+50% TLP vs r14's 16) to hide the step-phase
//   LDS latency that keeps r14's steps ~5x above throughput floor.
// Unlike r13 (which tested 4 blocks/CU at a 64-VGPR budget and regressed),
// this point keeps an 85-VGPR budget -- __launch_bounds__(512,3), knob
// ledger semantics: 2nd arg = blocks/CU -> 24-wave target -> 512/6 = 85.
// Weights stay PACKED fp16 (r8/r12-proven correct, absmax 1.0):
// persistent = wp 24 + Cc 6 + pr 3 = 33 + ~25 temps ~= 58 < 85, no spill.
// fmaf(__low2float(w),..) compiles to v_fma_mix_f32 (cvt folded into FMA).
// Cost: redundancy 11.6 px-steps/output-px vs r14's 10.9 (+7%).
//
//  - Pairs start at odd region col -> all +-RJ+-1 tap bases even -> 8B
//    aligned (RJ=56 even preserves parity across rows).
//  - Shrinking active set, pair-granular (r8/r11/r14-verified): compute
//    pair if max(ring0,ring1) >= s; partner px below cutoff computes
//    bounded stale values never read by in-cutoff px later. Final step
//    exact per-px center checks (mring>=8 -> ri in [8,40) = 32 rows;
//    cols gated per px to [8,48) = 40 cols).
//  - Out-of-image region px hold clamped duplicates; never reach the
//    center (image-boundary px have weight 0 toward OOB neighbors).
//  - blur/din NOT __restrict__ (r11 aliasing fix); launch 1 FIRST=true.
template <bool FIRST>
__global__ __launch_bounds__(BLOCK, 3)
void mega(
    const __half* __restrict__ wbuf,
    const float* __restrict__ cbuf,
    const float* blur,
    const float* din,
    float* __restrict__ dout)
{
    __shared__ float sd[2][RR];

    const int tid = threadIdx.x;
    // XCD-aware bijective swizzle (768 = 8*96).
    int bx = ((int)blockIdx.x % NXCD) * CHUNK + (int)blockIdx.x / NXCD;
    const int tj = bx % TJ_T; bx /= TJ_T;
    const int ti = bx % TI_T;
    const int b  = bx / TI_T;
    const int oi = ti * TILE_I - S_STEPS;  // region origin (image coords)
    const int oj = tj * TILE_J - S_STEPS;

    const float* dinb = (FIRST ? blur : din) + (size_t)b * HW;

    // --- stage d0 over the whole region (image-clamped) ---
#pragma unroll
    for (int q = 0; q < PPQ; q++) {
        int p = tid + q * BLOCK;
        if (p < RR) {
            int ri = p / RJ, rj = p - ri * RJ;
            int gi = iclamp(oi + ri, 0, Hh - 1);
            int gj = iclamp(oj + rj, 0, Ww - 1);
            sd[0][p] = dinb[gi * Ww + gj];
        }
    }

    // --- load precomputed fp16 weights (stay packed) + C per PAIR.
    // wp[q][k] = half2( w_k[px0], w_k[px1] ); Cc[q] = (C0, C1);
    // pr[q] = region offset of px0 (low 16) | max(ring0,ring1) << 16 ---
    __half2 wp[PPR][8];
    float2  Cc[PPR];
    int     pr[PPR];
#pragma unroll
    for (int q = 0; q < PPR; q++) {
        int pi = tid + q * BLOCK;
        if (pi < NPAIR) {
            int r0 = pi / NPAIR_ROW;
            int c0 = pi - r0 * NPAIR_ROW;
            int ri = 1 + r0;
            int rj = 1 + 2 * c0;           // odd -> aligned b64 tap bases
            int p  = ri * RJ + rj;
            int rngr = min(ri, RI - 1 - ri);
            int rng0 = min(rngr, min(rj,     RJ - 1 - rj));
            int rng1 = min(rngr, min(rj + 1, RJ - 2 - rj));
            pr[q] = p | (max(rng0, rng1) << 16);
            // px0 / px1 fp16x8 weight records, repacked pairwise:
            int gi = iclamp(oi + ri, 0, Hh - 1);
            int gj0 = iclamp(oj + rj,     0, Ww - 1);
            int gj1 = iclamp(oj + rj + 1, 0, Ww - 1);
            int idx0 = b * HW + gi * Ww + gj0;
            int idx1 = b * HW + gi * Ww + gj1;
            float4 wA = *(const float4*)(wbuf + (size_t)idx0 * 8);
            float4 wB = *(const float4*)(wbuf + (size_t)idx1 * 8);
            const __half* ha = (const __half*)&wA;
            const __half* hb = (const __half*)&wB;
#pragma unroll
            for (int k = 0; k < 8; k++)
                wp[q][k] = __halves2half2(ha[k], hb[k]);
            Cc[q] = make_float2(cbuf[idx0], cbuf[idx1]);
        } else {
            pr[q] = 0;                      // ring 0 -> never active
            Cc[q] = make_float2(0.0f, 0.0f);
#pragma unroll
            for (int k = 0; k < 8; k++)
                wp[q][k] = __halves2half2(__float2half(0.0f), __float2half(0.0f));
        }
    }
    __syncthreads();

    // --- steps 1..7 in LDS; step s touches only pairs with maxring >= s ---
    int cur = 0;
#pragma unroll 1
    for (int s = 1; s < S_STEPS; ++s) {
        const float* s0 = sd[cur];
        float* s1 = sd[cur ^ 1];
#pragma unroll
        for (int q = 0; q < PPR; q++) {
            if ((pr[q] >> 16) >= s) {
                int p = pr[q] & 0xffff;
                // 12 distinct taps as 6 aligned b64 loads
                float2 uA = *(const float2*)(s0 + p - RJ - 1);   // (i-1: j-1, j)
                float2 uB = *(const float2*)(s0 + p - RJ + 1);   // (i-1: j+1, j+2)
                float2 mA = *(const float2*)(s0 + p - 1);        // (i  : j-1, j)
                float2 mB = *(const float2*)(s0 + p + 1);        // (i  : j+1, j+2)
                float2 dA = *(const float2*)(s0 + p + RJ - 1);   // (i+1: j-1, j)
                float2 dB = *(const float2*)(s0 + p + RJ + 1);   // (i+1: j+1, j+2)
                float ax = Cc[q].x, ay = Cc[q].y;
                ax = fmaf(__low2float (wp[q][0]), dB.x, ax);
                ay = fmaf(__high2float(wp[q][0]), dB.y, ay);
                ax = fmaf(__low2float (wp[q][1]), dA.y, ax);
                ay = fmaf(__high2float(wp[q][1]), dB.x, ay);
                ax = fmaf(__low2float (wp[q][2]), dA.x, ax);
                ay = fmaf(__high2float(wp[q][2]), dA.y, ay);
                ax = fmaf(__low2float (wp[q][3]), mB.x, ax);
                ay = fmaf(__high2float(wp[q][3]), mB.y, ay);
                ax = fmaf(__low2float (wp[q][4]), mA.x, ax);
                ay = fmaf(__high2float(wp[q][4]), mA.y, ay);
                ax = fmaf(__low2float (wp[q][5]), uB.x, ax);
                ay = fmaf(__high2float(wp[q][5]), uB.y, ay);
                ax = fmaf(__low2float (wp[q][6]), uA.y, ax);
                ay = fmaf(__high2float(wp[q][6]), uB.x, ay);
                ax = fmaf(__low2float (wp[q][7]), uA.x, ax);
                ay = fmaf(__high2float(wp[q][7]), uA.y, ay);
                s1[p]     = ax;
                s1[p + 1] = ay;
            }
        }
        __syncthreads();
        cur ^= 1;
    }

    // --- step 8: per-px center checks, write straight to global ---
    const float* s0 = sd[cur];
#pragma unroll
    for (int q = 0; q < PPR; q++) {
        if ((pr[q] >> 16) >= S_STEPS) {
            int p = pr[q] & 0xffff;
            float2 uA = *(const float2*)(s0 + p - RJ - 1);
            float2 uB = *(const float2*)(s0 + p - RJ + 1);
            float2 mA = *(const float2*)(s0 + p - 1);
            float2 mB = *(const float2*)(s0 + p + 1);
            float2 dA = *(const float2*)(s0 + p + RJ - 1);
            float2 dB = *(const float2*)(s0 + p + RJ + 1);
            float ax = Cc[q].x, ay = Cc[q].y;
            ax = fmaf(__low2float (wp[q][0]), dB.x, ax);
            ay = fmaf(__high2float(wp[q][0]), dB.y, ay);
            ax = fmaf(__low2float (wp[q][1]), dA.y, ax);
            ay = fmaf(__high2float(wp[q][1]), dB.x, ay);
            ax = fmaf(__low2float (wp[q][2]), dA.x, ax);
            ay = fmaf(__high2float(wp[q][2]), dA.y, ay);
            ax = fmaf(__low2float (wp[q][3]), mB.x, ax);
            ay = fmaf(__high2float(wp[q][3]), mB.y, ay);
            ax = fmaf(__low2float (wp[q][4]), mA.x, ax);
            ay = fmaf(__high2float(wp[q][4]), mA.y, ay);
            ax = fmaf(__low2float (wp[q][5]), uB.x, ax);
            ay = fmaf(__high2float(wp[q][5]), uB.y, ay);
            ax = fmaf(__low2float (wp[q][6]), uA.y, ax);
            ay = fmaf(__high2float(wp[q][6]), uB.x, ay);
            ax = fmaf(__low2float (wp[q][7]), uA.x, ax);
            ay = fmaf(__high2float(wp[q][7]), uA.y, ay);
            int ri = p / RJ, rj = p - ri * RJ;
            // mring >= 8 guarantees ri in [8, RI-8); cols checked per px.
            int gbase = b * HW + (oi + ri) * Ww + (oj + rj);
            if (rj >= S_STEPS && rj < RJ - S_STEPS)
                dout[gbase]     = ax;
            if (rj + 1 >= S_STEPS && rj + 1 < RJ - S_STEPS)
                dout[gbase + 1] = ay;
        }
    }
}

extern "C" void kernel_launch(void* const* d_in, const int* in_sizes, int n_in,
                              void* d_out, int out_size, void* d_ws, size_t ws_size,
                              hipStream_t stream) {
    const float* guidance = (const float*)d_in[0];
    const float* blur     = (const float*)d_in[1];
    const float* sparse   = (const float*)d_in[2];
    float* out = (float*)d_out;

    char* ws = (char*)d_ws;
    float* bufA = (float*)ws;
    float* bufB = bufA + NPIX;
    __half* wbuf = (__half*)(bufB + NPIX);          // NPIX*8 fp16 = 15.7 MB
    float*  cbuf = (float*)(wbuf + (size_t)NPIX * 8);

    const int threads = 256;
    const int blocks = (NPIX + threads - 1) / threads;
    affinity_norm<<<blocks, threads, 0, stream>>>(guidance, blur, sparse, wbuf, cbuf);

    // 24 steps = 3 launches x 8 fused steps
    mega<true ><<<GRID, BLOCK, 0, stream>>>(wbuf, cbuf, blur, nullptr, bufA);
    mega<false><<<GRID, BLOCK, 0, stream>>>(wbuf, cbuf, nullptr, bufA, bufB);
    mega<false><<<GRID, BLOCK, 0, stream>>>(wbuf, cbuf, nullptr, bufB, out);
}